// Round 7
// baseline (88.398 us; speedup 1.0000x reference)
//
#include <hip/hip_runtime.h>

// Capsule agreement routing, fp32.
// preds [8,32,14,14,32,16], b [1,32,14,14,32], out v [8,32,14,14,16].
//
// 16 sites per 64-lane wave; lane (s_w = lane>>2, q = lane&3) owns rows
// i = q + 4k (k=0..7, stride-4 interleave) x all 16 d of site s_w
// (128 floats resident in VGPRs for all 4 routing passes).
//
// Staging: global_load_lds (zero staging VGPRs) in 4 row-phases of 8 KB
// (phase ph = rows [8ph, 8ph+8) of all 16 sites). LDS dest is linear
// (wave-uniform base + lane*16); the XOR swizzle is applied to the GLOBAL
// source address and identically on the ds_read (same involution both
// sides — rule "both-sides-or-neither").
//   LDS slot (f4) for (site x, phase-row j, comp u) = x*32 + ((j*4+u) ^ (x&7))
//   read (fixed m,u): bank-group = (4(q&1)+u) ^ (s_w&7) -> 8 lanes/group
//     (2-way for b128 = free); write side is the linear DMA (conflict-free).
//   Stride-4 row ownership => every phase gives EVERY lane 2 rows: all
//   ds_reads are full-wave (no exec masking).
// Per-wave 8 KB slice, 32 KB/block; __launch_bounds__(256,3) targets
// VGPR<=168 -> 12 waves/CU resident vs 12.25 needed = ~1 generation.
//
// Math per pass (all cross-lane = quad_perm DPP, zero LDS-pipe ops):
//   b in log2 domain -> e = exp2(bl) is a bare v_exp_f32 (e fused into the
//   s-accumulate loop, no e[] array)
//   softmax sum: 8 local adds + 2 DPP; r = rcp(sum) folded into squash
//   s~_d = sum_i e_i p_id : 128 lane-local FMA + quad-reduce (2 DPP/comp)
//   squash: sq = r^2|s~|^2, f = sq/(1+sq)/sqrt(sq+eps)*r ; v = f*s~
//   agreement: bl_i += (f*log2e) * dot(p_i, s~) -- fully lane-local
// v materialized only in the epilogue (all 64 lanes store one float4:
// contiguous 1 KB per wave).

#define EPSQ 1e-7f
#define LOG2E 1.442695041f

constexpr int OHW   = 6272;           // 32*14*14
constexpr int SITES = 50176;          // 8 * OHW
constexpr int THREADS = 256;
constexpr int BLOCKS  = SITES / 64;   // 784 (16 sites/wave * 4 waves/block)

__device__ __forceinline__ float dpp1(float x) {   // quad_perm xor 1
    return __int_as_float(__builtin_amdgcn_mov_dpp(__float_as_int(x), 0xB1, 0xF, 0xF, true));
}
__device__ __forceinline__ float dpp2(float x) {   // quad_perm xor 2
    return __int_as_float(__builtin_amdgcn_mov_dpp(__float_as_int(x), 0x4E, 0xF, 0xF, true));
}
__device__ __forceinline__ void fma4(float4& a, float c, const float4& x) {
    a.x = fmaf(c, x.x, a.x); a.y = fmaf(c, x.y, a.y);
    a.z = fmaf(c, x.z, a.z); a.w = fmaf(c, x.w, a.w);
}
__device__ __forceinline__ float dot4(const float4& a, const float4& b) {
    return fmaf(a.x, b.x, fmaf(a.y, b.y, fmaf(a.z, b.z, a.w * b.w)));
}
__device__ __forceinline__ void qred4(float4& a) {
    a.x += dpp1(a.x); a.y += dpp1(a.y); a.z += dpp1(a.z); a.w += dpp1(a.w);
    a.x += dpp2(a.x); a.y += dpp2(a.y); a.z += dpp2(a.z); a.w += dpp2(a.w);
}

__device__ __forceinline__ void gload16(const float4* g, float4* l) {
    __builtin_amdgcn_global_load_lds(
        (const __attribute__((address_space(1))) void*)g,
        (__attribute__((address_space(3))) void*)l, 16, 0, 0);
}

__global__ __launch_bounds__(256, 3) void routing_kernel(
    const float* __restrict__ preds,
    const float* __restrict__ bparam,
    float* __restrict__ out)
{
    __shared__ float4 lds4[2048];     // 32 KB = 4 waves x 512 float4 (8 KB)
    const int tid  = threadIdx.x;
    const int lane = tid & 63;
    const int wib  = tid >> 6;
    const int wave = blockIdx.x * 4 + wib;
    const int q    = lane & 3;        // row class: rows q, q+4, ..., q+28
    const int s_w  = lane >> 2;       // within-wave site 0..15
    const int site = wave * 16 + s_w;

    float4* wlds = lds4 + wib * 512;
    const float4* pg = (const float4*)preds + (size_t)wave * 2048;  // 16 sites * 128 f4

    // per-lane global source f4-offsets for the 8 DMA instructions of a phase:
    // instr t covers LDS slots [t*64, t*64+64); slot pos = t*64 + lane;
    // x = pos>>5 = 2t + (lane>>5), w = pos&31;
    // src f4 = x*128 + 32*ph + (w ^ (x&7))   (inverse of the read swizzle)
    const int hi  = lane >> 5;
    const int w32 = lane & 31;
    int soff[8];
    #pragma unroll
    for (int t = 0; t < 8; ++t) {
        const int x = 2 * t + hi;
        soff[t] = x * 128 + (w32 ^ (x & 7));
    }

    // issue phase 0 DMA immediately
    #pragma unroll
    for (int t = 0; t < 8; ++t) gload16(pg + soff[t], wlds + t * 64);

    // routing logits for rows q+4k (scalar, L1/L2-resident, 8x batch reuse)
    const int sohw = site % OHW;
    const float* bs = bparam + (size_t)sohw * 32 + q;
    float bl[8];
    #pragma unroll
    for (int k = 0; k < 8; ++k) bl[k] = bs[4 * k] * LOG2E;

    // ---- 4 row-phases: wait DMA -> full-wave swizzled reads -> issue next
    float4 p[8][4];                   // p[k][u] = row q+4k, comps 4u..4u+3
    const int rbase = s_w * 32;
    const int rkey  = s_w & 7;
    #pragma unroll
    for (int ph = 0; ph < 4; ++ph) {
        asm volatile("s_waitcnt vmcnt(0)" ::: "memory");
        #pragma unroll
        for (int m = 0; m < 2; ++m) {
            const int j = q + 4 * m;              // phase-local row
            #pragma unroll
            for (int u = 0; u < 4; ++u)
                p[2 * ph + m][u] = wlds[rbase + ((j * 4 + u) ^ rkey)];
        }
        if (ph < 3) {
            asm volatile("s_waitcnt lgkmcnt(0)" ::: "memory");  // reads landed; buffer free
            #pragma unroll
            for (int t = 0; t < 8; ++t)
                gload16(pg + (soff[t] + 32 * (ph + 1)), wlds + t * 64);
        }
    }

    float4 s0, s1, s2, s3;            // unnormalized s~, replicated across quad
    float  f;                         // v = f * s~

    auto pass = [&]() {
        float sm = 0.0f;
        s0 = make_float4(0,0,0,0); s1 = make_float4(0,0,0,0);
        s2 = make_float4(0,0,0,0); s3 = make_float4(0,0,0,0);
        #pragma unroll
        for (int k = 0; k < 8; ++k) {
            const float e = __builtin_amdgcn_exp2f(bl[k]);
            sm += e;
            fma4(s0, e, p[k][0]); fma4(s1, e, p[k][1]);
            fma4(s2, e, p[k][2]); fma4(s3, e, p[k][3]);
        }
        sm += dpp1(sm);
        sm += dpp2(sm);
        const float r = __frcp_rn(sm);
        qred4(s0); qred4(s1); qred4(s2); qred4(s3);

        const float sqt = dot4(s0, s0) + dot4(s1, s1) + dot4(s2, s2) + dot4(s3, s3);
        const float sq  = r * r * sqt;
        f = sq * __frcp_rn(1.0f + sq) * __frsqrt_rn(sq + EPSQ) * r;
    };

    pass();

    #pragma unroll
    for (int it = 0; it < 3; ++it) {
        const float fl = f * LOG2E;
        #pragma unroll
        for (int k = 0; k < 8; ++k) {
            const float qk = dot4(p[k][0], s0) + dot4(p[k][1], s1)
                           + dot4(p[k][2], s2) + dot4(p[k][3], s3);
            bl[k] = fmaf(fl, qk, bl[k]);
        }
        pass();
    }

    // epilogue: all 64 lanes store one float4 -> contiguous 1 KB per wave
    // out f4 index = site*4 + q = wave*64 + lane
    float4 w = (q == 0) ? s0 : (q == 1) ? s1 : (q == 2) ? s2 : s3;
    w.x *= f; w.y *= f; w.z *= f; w.w *= f;
    ((float4*)out)[(size_t)wave * 64 + lane] = w;
}

extern "C" void kernel_launch(void* const* d_in, const int* in_sizes, int n_in,
                              void* d_out, int out_size, void* d_ws, size_t ws_size,
                              hipStream_t stream) {
    const float* preds  = (const float*)d_in[0];
    const float* bparam = (const float*)d_in[1];
    float* out = (float*)d_out;
    routing_kernel<<<BLOCKS, THREADS, 0, stream>>>(preds, bparam, out);
}

// Round 8
// 27.727 us; speedup vs baseline: 3.1882x; 3.1882x over previous
//
#include <hip/hip_runtime.h>

// Capsule agreement routing, fp32.
// preds [8,32,14,14,32,16], b [1,32,14,14,32], out v [8,32,14,14,16].
//
// 16 sites per 64-lane wave; lane (s_w = lane>>2, q = lane&3) owns rows
// i = q + 4k (k=0..7, stride-4 interleave) x all 16 d of site s_w
// (128 floats resident in VGPRs for all 4 routing passes).
//
// Staging: global_load_lds (zero staging VGPRs), 4 row-phases of 8 KB,
// DOUBLE-BUFFERED (A/B, 16 KB/wave) with counted vmcnt so 8-16 loads stay
// in flight continuously:
//   issue b(8), ph0->A(8), ph1->B(8)            | outstanding 24
//   vmcnt(8)  -> read ph0(A); lgkm(0); ph2->A   | 16
//   vmcnt(8)  -> read ph1(B); lgkm(0); ph3->B   | 16
//   vmcnt(8)  -> read ph2(A)                    | 8
//   vmcnt(0)  -> read ph3(B)                    | 0
// LDS dest is linear (DMA); XOR swizzle applied to the GLOBAL source and
// identically on the ds_read (both-sides involution):
//   slot(f4) for (site x, phase-row j, comp u) = x*32 + ((j*4+u) ^ (x&7))
//   read (fixed m,u): bank-group = (4(q&1)+u) ^ (s_w&7) -> 8 lanes/group
//   (2-way per b128 = free). Stride-4 row ownership => every phase gives
//   every lane 2 rows: all ds_reads full-wave, no exec masking.
// __launch_bounds__(256,2): 256-VGPR budget -- the R7 regression was a
// spill (WRITE_SIZE 145 MB of scratch) from the 168-cap at (256,3).
// LDS 64 KB/block -> 2 blocks/CU, matches VGPR occupancy.
//
// Math per pass (all cross-lane = quad_perm DPP, zero LDS-pipe ops):
//   b in log2 domain -> e = exp2(bl), fused into the s-accumulate
//   softmax sum: 8 local adds + 2 DPP; r = rcp(sum) folded into squash
//   s~_d = sum_i e_i p_id : 128 lane-local FMA + quad-reduce (2 DPP/comp)
//   squash: sq = r^2|s~|^2, f = sq/(1+sq)/sqrt(sq+eps)*r ; v = f*s~
//   agreement: bl_i += (f*log2e) * dot(p_i, s~) -- fully lane-local
// All 64 lanes store one float4 in the epilogue (contiguous 1 KB/wave).

#define EPSQ 1e-7f
#define LOG2E 1.442695041f

constexpr int OHW   = 6272;           // 32*14*14
constexpr int SITES = 50176;          // 8 * OHW
constexpr int THREADS = 256;
constexpr int BLOCKS  = SITES / 64;   // 784 (16 sites/wave * 4 waves/block)

__device__ __forceinline__ float dpp1(float x) {   // quad_perm xor 1
    return __int_as_float(__builtin_amdgcn_mov_dpp(__float_as_int(x), 0xB1, 0xF, 0xF, true));
}
__device__ __forceinline__ float dpp2(float x) {   // quad_perm xor 2
    return __int_as_float(__builtin_amdgcn_mov_dpp(__float_as_int(x), 0x4E, 0xF, 0xF, true));
}
__device__ __forceinline__ void fma4(float4& a, float c, const float4& x) {
    a.x = fmaf(c, x.x, a.x); a.y = fmaf(c, x.y, a.y);
    a.z = fmaf(c, x.z, a.z); a.w = fmaf(c, x.w, a.w);
}
__device__ __forceinline__ float dot4(const float4& a, const float4& b) {
    return fmaf(a.x, b.x, fmaf(a.y, b.y, fmaf(a.z, b.z, a.w * b.w)));
}
__device__ __forceinline__ void qred4(float4& a) {
    a.x += dpp1(a.x); a.y += dpp1(a.y); a.z += dpp1(a.z); a.w += dpp1(a.w);
    a.x += dpp2(a.x); a.y += dpp2(a.y); a.z += dpp2(a.z); a.w += dpp2(a.w);
}

__device__ __forceinline__ void gload16(const float4* g, float4* l) {
    __builtin_amdgcn_global_load_lds(
        (const __attribute__((address_space(1))) void*)g,
        (__attribute__((address_space(3))) void*)l, 16, 0, 0);
}

__global__ __launch_bounds__(256, 2) void routing_kernel(
    const float* __restrict__ preds,
    const float* __restrict__ bparam,
    float* __restrict__ out)
{
    __shared__ float4 lds4[4096];     // 64 KB = 4 waves x 2 bufs x 512 f4
    const int tid  = threadIdx.x;
    const int lane = tid & 63;
    const int wib  = tid >> 6;
    const int wave = blockIdx.x * 4 + wib;
    const int q    = lane & 3;        // row class: rows q, q+4, ..., q+28
    const int s_w  = lane >> 2;       // within-wave site 0..15
    const int site = wave * 16 + s_w;

    float4* bufA = lds4 + wib * 512;
    float4* bufB = lds4 + 2048 + wib * 512;
    const float4* pg = (const float4*)preds + (size_t)wave * 2048;  // 16 sites*128 f4

    // ---- routing logits FIRST (oldest 8 entries in the vmcnt queue)
    const int sohw = site % OHW;
    const float* bs = bparam + (size_t)sohw * 32 + q;
    float bl[8];
    #pragma unroll
    for (int k = 0; k < 8; ++k) bl[k] = bs[4 * k];

    // per-lane global source f4-offsets for one phase's 8 DMA instructions:
    // instr t covers LDS slots [t*64, t*64+64); pos = t*64+lane;
    // x = 2t + (lane>>5), w = pos&31; src f4 = x*128 + 32*ph + (w ^ (x&7))
    const int hi  = lane >> 5;
    const int w32 = lane & 31;
    int soff[8];
    #pragma unroll
    for (int t = 0; t < 8; ++t) {
        const int x = 2 * t + hi;
        soff[t] = x * 128 + (w32 ^ (x & 7));
    }

    // ---- prologue: ph0 -> A, ph1 -> B (24 vmem ops in flight incl. b)
    #pragma unroll
    for (int t = 0; t < 8; ++t) gload16(pg + soff[t], bufA + t * 64);
    #pragma unroll
    for (int t = 0; t < 8; ++t) gload16(pg + soff[t] + 32, bufB + t * 64);

    float4 p[8][4];                   // p[k][u] = row q+4k, comps 4u..4u+3
    const int rbase = s_w * 32;
    const int rkey  = s_w & 7;

    auto read_phase = [&](int ph, const float4* buf) {
        #pragma unroll
        for (int m = 0; m < 2; ++m) {
            const int j = q + 4 * m;              // phase-local row
            #pragma unroll
            for (int u = 0; u < 4; ++u)
                p[2 * ph + m][u] = buf[rbase + ((j * 4 + u) ^ rkey)];
        }
    };

    asm volatile("s_waitcnt vmcnt(8)" ::: "memory");    // b + ph0 landed
    read_phase(0, bufA);
    asm volatile("s_waitcnt lgkmcnt(0)" ::: "memory");  // A reads in regs
    #pragma unroll
    for (int t = 0; t < 8; ++t) gload16(pg + soff[t] + 64, bufA + t * 64);   // ph2

    asm volatile("s_waitcnt vmcnt(8)" ::: "memory");    // ph1 landed
    read_phase(1, bufB);
    asm volatile("s_waitcnt lgkmcnt(0)" ::: "memory");  // B reads in regs
    #pragma unroll
    for (int t = 0; t < 8; ++t) gload16(pg + soff[t] + 96, bufB + t * 64);   // ph3

    asm volatile("s_waitcnt vmcnt(8)" ::: "memory");    // ph2 landed
    read_phase(2, bufA);
    asm volatile("s_waitcnt vmcnt(0)" ::: "memory");    // ph3 landed
    read_phase(3, bufB);
    // (compiler inserts its own lgkmcnt before first use of p)

    // logits -> log2 domain
    #pragma unroll
    for (int k = 0; k < 8; ++k) bl[k] *= LOG2E;

    float4 s0, s1, s2, s3;            // unnormalized s~, replicated across quad
    float  f;                         // v = f * s~

    auto pass = [&]() {
        float sm = 0.0f;
        s0 = make_float4(0,0,0,0); s1 = make_float4(0,0,0,0);
        s2 = make_float4(0,0,0,0); s3 = make_float4(0,0,0,0);
        #pragma unroll
        for (int k = 0; k < 8; ++k) {
            const float e = __builtin_amdgcn_exp2f(bl[k]);
            sm += e;
            fma4(s0, e, p[k][0]); fma4(s1, e, p[k][1]);
            fma4(s2, e, p[k][2]); fma4(s3, e, p[k][3]);
        }
        sm += dpp1(sm);
        sm += dpp2(sm);
        const float r = __frcp_rn(sm);
        qred4(s0); qred4(s1); qred4(s2); qred4(s3);

        const float sqt = dot4(s0, s0) + dot4(s1, s1) + dot4(s2, s2) + dot4(s3, s3);
        const float sq  = r * r * sqt;
        f = sq * __frcp_rn(1.0f + sq) * __frsqrt_rn(sq + EPSQ) * r;
    };

    pass();

    #pragma unroll
    for (int it = 0; it < 3; ++it) {
        const float fl = f * LOG2E;
        #pragma unroll
        for (int k = 0; k < 8; ++k) {
            const float qk = dot4(p[k][0], s0) + dot4(p[k][1], s1)
                           + dot4(p[k][2], s2) + dot4(p[k][3], s3);
            bl[k] = fmaf(fl, qk, bl[k]);
        }
        pass();
    }

    // epilogue: all 64 lanes store one float4 -> contiguous 1 KB per wave
    // out f4 index = site*4 + q = wave*64 + lane
    float4 w = (q == 0) ? s0 : (q == 1) ? s1 : (q == 2) ? s2 : s3;
    w.x *= f; w.y *= f; w.z *= f; w.w *= f;
    ((float4*)out)[(size_t)wave * 64 + lane] = w;
}

extern "C" void kernel_launch(void* const* d_in, const int* in_sizes, int n_in,
                              void* d_out, int out_size, void* d_ws, size_t ws_size,
                              hipStream_t stream) {
    const float* preds  = (const float*)d_in[0];
    const float* bparam = (const float*)d_in[1];
    float* out = (float*)d_out;
    routing_kernel<<<BLOCKS, THREADS, 0, stream>>>(preds, bparam, out);
}